// Round 16
// baseline (50.061 us; speedup 1.0000x reference)
//
#include <hip/hip_runtime.h>
#include <hip/hip_bf16.h>
#include <stdint.h>

// ---------------------------------------------------------------------------
// out[b,t,a,:] = (state_in[b,t,a,:] @ readin[session[b]]) @ project
// SINGLE fused kernel. 512 thr = 8 waves, wave strip = 16 rows -> 16 waves/CU
// (4/SIMD). M-tile 256, grid 1024 = b(128) x mt(4) x nt(2).
// Prologue: W[i][o] via swapped MFMA from LDS-staged R,P; b64 W-store into
//   Bs[kslot][row]; A stage(0)/stage(1) issued at kernel start.
// Main: 12 flat steps = 2 halves x 6 K-steps, zero barriers, counted vmcnt
//   (VM2 steady; VM10 when boundary stores are in the younger window; VM0
//   last). mfma(bfr, af) -> D[o][m] -> per-half 8x NONTEMPORAL
//   global_store_dwordx4 (Y is streaming, never re-read: keep L2 for X/W).
// LDS 80KB: Bs 48KB @0 (Rl/Pl overlay) | A 8 waves x 2 x 2KB @49152.
// ---------------------------------------------------------------------------

typedef short    bf16x8 __attribute__((ext_vector_type(8)));
typedef float    f32x4  __attribute__((ext_vector_type(4)));
typedef uint32_t u32x2  __attribute__((ext_vector_type(2)));
typedef uint32_t u32x4  __attribute__((ext_vector_type(4)));

#define NB    128
#define MPB   1024
#define INF   192
#define RDIM  64
#define OUTF  256

#define WAIT_VM10()  asm volatile("s_waitcnt vmcnt(10)" ::: "memory")
#define WAIT_VM2()   asm volatile("s_waitcnt vmcnt(2)" ::: "memory")
#define WAIT_VM0()   asm volatile("s_waitcnt vmcnt(0)" ::: "memory")
#define WAIT_LGKM0() asm volatile("s_waitcnt lgkmcnt(0)" ::: "memory")

__device__ __forceinline__ uint16_t f2bf(float f) {
    union { float f; uint32_t u; } v; v.f = f;
    return (uint16_t)((v.u + 0x7fffu + ((v.u >> 16) & 1u)) >> 16);
}
__device__ __forceinline__ uint32_t pack2(float a, float b) {
    return (uint32_t)f2bf(a) | ((uint32_t)f2bf(b) << 16);
}
__device__ __forceinline__ bf16x8 cvt8(f32x4 a, f32x4 b) {
    union { __hip_bfloat162 h2[4]; bf16x8 h; } r;
    r.h2[0] = __float22bfloat162_rn({a[0], a[1]});
    r.h2[1] = __float22bfloat162_rn({a[2], a[3]});
    r.h2[2] = __float22bfloat162_rn({b[0], b[1]});
    r.h2[3] = __float22bfloat162_rn({b[2], b[3]});
    return r.h;
}
__device__ __forceinline__ void gl_lds16(const void* g, void* l) {
    auto gp = (const __attribute__((address_space(1))) uint32_t*)(uintptr_t)g;
    auto lp = (__attribute__((address_space(3))) uint32_t*)(uintptr_t)l;
    __builtin_amdgcn_global_load_lds(gp, lp, 16, 0, 0);
}

__global__ __launch_bounds__(512, 2) void fused_gemm(
    const float* __restrict__ X,        // [128][1024][192]
    const int*   __restrict__ session,  // [128]
    const float* __restrict__ readin,   // [512][192][64]
    const float* __restrict__ project,  // [64][256]
    float*       __restrict__ Y)        // [128][1024][256]
{
    __shared__ __attribute__((aligned(16))) uint8_t arena[81920];

    const int bid0 = blockIdx.x;
    const int bid  = ((bid0 & 7) << 7) | (bid0 >> 3);   // bijective (1024%8==0)
    const int b  = bid >> 3;
    const int mt = (bid >> 1) & 3;                       // 256-row tiles
    const int nt = bid & 1;
    const int t  = threadIdx.x, l = t & 63, w = t >> 6;  // 8 waves
    const int lr = l & 15, lk = l >> 4;

    const float* Xb = X + ((size_t)b * MPB + mt * 256) * INF;
    float*       Yb = Y + ((size_t)b * MPB + mt * 256) * OUTF + nt * 128;

    // ---- A staging: wave strip 16 rows; 2 bufs x 2KB @49152 ---------------
    uint8_t* Ab = arena + 49152 + w * 4096;
    int asrc[2];
#pragma unroll
    for (int c = 0; c < 2; ++c) {
        int i   = c * 64 + l;
        int row = i >> 3;                  // 0..15
        int kq  = (i & 7) ^ (row & 7);
        asrc[c] = row * INF + kq * 4;
    }
    const float* Aw = Xb + (size_t)(w * 16) * INF;

    auto stage = [&](int s, int buf) {     // s compile-time under unroll
        const float* src = Aw + (s / 6) * (128 * INF) + (s % 6) * 32;
#pragma unroll
        for (int c = 0; c < 2; ++c)
            gl_lds16(src + asrc[c], Ab + buf * 2048 + c * 1024);
    };

    stage(0, 0);
    stage(1, 1);

    // ================= prologue: W panel -> Bs (bf16, [kslot][row]) =========
    {
        uint16_t* Rl = (uint16_t*)arena;             // [192][64] swz, 24KB @0
        uint16_t* Pl = (uint16_t*)(arena + 24576);   // [128][64] swz, 16KB
        const float* Rg = readin + (size_t)session[b] * (INF * RDIM);

        // stage R (192x64 f32 -> bf16, XOR-swizzled), 8 f32/thread x 3
#pragma unroll
        for (int c = 0; c < 3; ++c) {
            int idx = c * 4096 + t * 8;
            int row = idx >> 6;
            int kg0 = t & 7;
            f32x4 v0 = *(const f32x4*)(Rg + idx);
            f32x4 v1 = *(const f32x4*)(Rg + idx + 4);
            u32x4 d0;
            d0[0] = pack2(v0[0], v0[1]); d0[1] = pack2(v0[2], v0[3]);
            d0[2] = pack2(v1[0], v1[1]); d0[3] = pack2(v1[2], v1[3]);
            *(u32x4*)&Rl[row * 64 + ((kg0 ^ (row & 7)) << 3)] = d0;
        }
        // stage P^T slice (o = nt*128 .. +128), 16 cols x 1 h per thread
        {
            int h  = t >> 3;               // 0..63
            int og = (t & 7) * 16;
            const float* Pg = project + (size_t)h * OUTF + nt * 128 + og;
#pragma unroll
            for (int q = 0; q < 4; ++q) {
                f32x4 v = *(const f32x4*)(Pg + q * 4);
#pragma unroll
                for (int e = 0; e < 4; ++e) {
                    int o = og + q * 4 + e;
                    Pl[o * 64 + (((h >> 3) ^ (o & 7)) << 3) + (h & 7)] = f2bf(v[e]);
                }
            }
        }
        __syncthreads();   // Rl/Pl ready (also drains A stage(0/1) vm ops)

        // 8-wave W split: wn = w&3 over i (4 x 48), wm = w>>2 over o (2 x 64)
        const int wn = w & 3, wm = w >> 2;
        f32x4 wacc[3][4];
#pragma unroll
        for (int n = 0; n < 3; ++n)
#pragma unroll
            for (int m = 0; m < 4; ++m) wacc[n][m] = f32x4{0.f, 0.f, 0.f, 0.f};

#pragma unroll
        for (int kk = 0; kk < 2; ++kk) {
            int kg = kk * 4 + lk;
            bf16x8 a[4], bb[3];
#pragma unroll
            for (int m = 0; m < 4; ++m) {
                int row = wm * 64 + m * 16 + lr;
                a[m] = *(const bf16x8*)&Pl[row * 64 + ((kg ^ (row & 7)) << 3)];
            }
#pragma unroll
            for (int n = 0; n < 3; ++n) {
                int col = wn * 48 + n * 16 + lr;
                bb[n] = *(const bf16x8*)&Rl[col * 64 + ((kg ^ (col & 7)) << 3)];
            }
#pragma unroll
            for (int n = 0; n < 3; ++n)
#pragma unroll
                for (int m = 0; m < 4; ++m)
                    wacc[n][m] = __builtin_amdgcn_mfma_f32_16x16x32_bf16(
                        bb[n], a[m], wacc[n][m], 0, 0, 0);
        }
        __syncthreads();   // all Rl/Pl reads complete before overwrite

        // store W: D[i = wn*48+n*16+lk*4+j][o = wm*64+m*16+lr] -> b64 each
        uint16_t* Bs16 = (uint16_t*)arena;
#pragma unroll
        for (int n = 0; n < 3; ++n) {
            int ubase = (wn * 6 + n * 2 + (lk >> 1)) * 128;
#pragma unroll
            for (int m = 0; m < 4; ++m) {
                int o = wm * 64 + m * 16 + lr;
                u32x2 d;
                d[0] = pack2(wacc[n][m][0], wacc[n][m][1]);
                d[1] = pack2(wacc[n][m][2], wacc[n][m][3]);
                *(u32x2*)&Bs16[(size_t)(ubase + o) * 8 + (lk & 1) * 4] = d;
            }
        }
        __syncthreads();   // Bs ready
    }

    // ================= main: 12 flat steps, zero barriers ===================
    f32x4 acc[8];
#pragma unroll
    for (int n = 0; n < 8; ++n) acc[n] = f32x4{0.f, 0.f, 0.f, 0.f};

    const int a0s = ((2 * lk)     ^ (lr & 7)) << 4;
    const int a1s = ((2 * lk + 1) ^ (lr & 7)) << 4;

#pragma unroll
    for (int s = 0; s < 12; ++s) {
        const int h  = s / 6;      // half 0..1
        const int kk = s % 6;      // K-step within half

        if (s == 11)                  { WAIT_VM0(); }
        else if (s == 6 || s == 7)    { WAIT_VM10(); }
        else                          { WAIT_VM2(); }
        __builtin_amdgcn_sched_barrier(0);

        const uint8_t* Abuf = Ab + (s & 1) * 2048;
        bf16x8 af, bfr[8];
        {
            const uint8_t* p = Abuf + lr * 128;
            f32x4 lo = *(const f32x4*)(p + a0s);
            f32x4 hi = *(const f32x4*)(p + a1s);
            af = cvt8(lo, hi);
        }
#pragma unroll
        for (int n = 0; n < 8; ++n)
            bfr[n] = *(const bf16x8*)(arena
                        + (((kk * 4 + lk) * 128 + n * 16 + lr) << 4));

        WAIT_LGKM0();                       // buf reads retired before reuse
        __builtin_amdgcn_sched_barrier(0);
        if (s < 10) stage(s + 2, s & 1);    // fire-and-forget, depth-2

        // swapped MFMA: D[o][m]; lane owns 4 consecutive o-cols
#pragma unroll
        for (int n = 0; n < 8; ++n)
            acc[n] = __builtin_amdgcn_mfma_f32_16x16x32_bf16(
                bfr[n], af, acc[n], 0, 0, 0);

        // half boundary: nontemporal store (Y never re-read; keep L2 for X/W)
        if (kk == 5) {
            float* yr = Yb + (size_t)(h * 128 + w * 16 + lr) * OUTF + lk * 4;
#pragma unroll
            for (int n = 0; n < 8; ++n)
                __builtin_nontemporal_store(acc[n], (f32x4*)(yr + n * 16));
            if (s != 11) {
#pragma unroll
                for (int n = 0; n < 8; ++n) acc[n] = f32x4{0.f, 0.f, 0.f, 0.f};
            }
        }
    }
}

extern "C" void kernel_launch(void* const* d_in, const int* in_sizes, int n_in,
                              void* d_out, int out_size, void* d_ws, size_t ws_size,
                              hipStream_t stream) {
    (void)in_sizes; (void)n_in; (void)out_size; (void)d_ws; (void)ws_size;
    const float* state   = (const float*)d_in[0];
    const int*   session = (const int*)  d_in[1];
    const float* readin  = (const float*)d_in[2];
    const float* project = (const float*)d_in[3];
    float*       out     = (float*)d_out;

    hipLaunchKernelGGL(fused_gemm, dim3(1024), dim3(512), 0, stream,
                       state, session, readin, project, out);
}

// Round 17
// 44.764 us; speedup vs baseline: 1.1183x; 1.1183x over previous
//
#include <hip/hip_runtime.h>
#include <hip/hip_bf16.h>
#include <stdint.h>

// ---------------------------------------------------------------------------
// out[b,t,a,:] = (state_in[b,t,a,:] @ readin[session[b]]) @ project
// SINGLE fused kernel (R15, best verified: 44.9 us bench / ~78 us profiled).
// 512 thr = 8 waves, wave strip = 16 rows -> 16 waves/CU (4/SIMD).
// M-tile 256, grid 1024 = b(128) x mt(4) x nt(2).
// Prologue: W[i][o] via swapped MFMA from LDS-staged R,P; b64 W-store into
//   Bs[kslot][row]; A stage(0)/stage(1) issued at kernel start.
// Main: 12 flat steps = 2 halves x 6 K-steps, zero barriers, counted vmcnt
//   (VM2 steady; VM10 when boundary stores are in the younger window; VM0
//   last). mfma(bfr, af) -> D[o][m] -> per-half 8x global_store_dwordx4
//   (NORMAL stores: R16 proved nontemporal hurts — L2 write-combining is load-
//   bearing, WRITE_SIZE 131->159MB and +5us with nt).
// LDS 80KB: Bs 48KB @0 (Rl/Pl overlay) | A 8 waves x 2 x 2KB @49152.
// ---------------------------------------------------------------------------

typedef short    bf16x8 __attribute__((ext_vector_type(8)));
typedef float    f32x4  __attribute__((ext_vector_type(4)));
typedef uint32_t u32x2  __attribute__((ext_vector_type(2)));
typedef uint32_t u32x4  __attribute__((ext_vector_type(4)));

#define NB    128
#define MPB   1024
#define INF   192
#define RDIM  64
#define OUTF  256

#define WAIT_VM10()  asm volatile("s_waitcnt vmcnt(10)" ::: "memory")
#define WAIT_VM2()   asm volatile("s_waitcnt vmcnt(2)" ::: "memory")
#define WAIT_VM0()   asm volatile("s_waitcnt vmcnt(0)" ::: "memory")
#define WAIT_LGKM0() asm volatile("s_waitcnt lgkmcnt(0)" ::: "memory")

__device__ __forceinline__ uint16_t f2bf(float f) {
    union { float f; uint32_t u; } v; v.f = f;
    return (uint16_t)((v.u + 0x7fffu + ((v.u >> 16) & 1u)) >> 16);
}
__device__ __forceinline__ uint32_t pack2(float a, float b) {
    return (uint32_t)f2bf(a) | ((uint32_t)f2bf(b) << 16);
}
__device__ __forceinline__ bf16x8 cvt8(f32x4 a, f32x4 b) {
    union { __hip_bfloat162 h2[4]; bf16x8 h; } r;
    r.h2[0] = __float22bfloat162_rn({a[0], a[1]});
    r.h2[1] = __float22bfloat162_rn({a[2], a[3]});
    r.h2[2] = __float22bfloat162_rn({b[0], b[1]});
    r.h2[3] = __float22bfloat162_rn({b[2], b[3]});
    return r.h;
}
__device__ __forceinline__ void gl_lds16(const void* g, void* l) {
    auto gp = (const __attribute__((address_space(1))) uint32_t*)(uintptr_t)g;
    auto lp = (__attribute__((address_space(3))) uint32_t*)(uintptr_t)l;
    __builtin_amdgcn_global_load_lds(gp, lp, 16, 0, 0);
}

__global__ __launch_bounds__(512, 2) void fused_gemm(
    const float* __restrict__ X,        // [128][1024][192]
    const int*   __restrict__ session,  // [128]
    const float* __restrict__ readin,   // [512][192][64]
    const float* __restrict__ project,  // [64][256]
    float*       __restrict__ Y)        // [128][1024][256]
{
    __shared__ __attribute__((aligned(16))) uint8_t arena[81920];

    const int bid0 = blockIdx.x;
    const int bid  = ((bid0 & 7) << 7) | (bid0 >> 3);   // bijective (1024%8==0)
    const int b  = bid >> 3;
    const int mt = (bid >> 1) & 3;                       // 256-row tiles
    const int nt = bid & 1;
    const int t  = threadIdx.x, l = t & 63, w = t >> 6;  // 8 waves
    const int lr = l & 15, lk = l >> 4;

    const float* Xb = X + ((size_t)b * MPB + mt * 256) * INF;
    float*       Yb = Y + ((size_t)b * MPB + mt * 256) * OUTF + nt * 128;

    // ---- A staging: wave strip 16 rows; 2 bufs x 2KB @49152 ---------------
    uint8_t* Ab = arena + 49152 + w * 4096;
    int asrc[2];
#pragma unroll
    for (int c = 0; c < 2; ++c) {
        int i   = c * 64 + l;
        int row = i >> 3;                  // 0..15
        int kq  = (i & 7) ^ (row & 7);
        asrc[c] = row * INF + kq * 4;
    }
    const float* Aw = Xb + (size_t)(w * 16) * INF;

    auto stage = [&](int s, int buf) {     // s compile-time under unroll
        const float* src = Aw + (s / 6) * (128 * INF) + (s % 6) * 32;
#pragma unroll
        for (int c = 0; c < 2; ++c)
            gl_lds16(src + asrc[c], Ab + buf * 2048 + c * 1024);
    };

    stage(0, 0);
    stage(1, 1);

    // ================= prologue: W panel -> Bs (bf16, [kslot][row]) =========
    {
        uint16_t* Rl = (uint16_t*)arena;             // [192][64] swz, 24KB @0
        uint16_t* Pl = (uint16_t*)(arena + 24576);   // [128][64] swz, 16KB
        const float* Rg = readin + (size_t)session[b] * (INF * RDIM);

        // stage R (192x64 f32 -> bf16, XOR-swizzled), 8 f32/thread x 3
#pragma unroll
        for (int c = 0; c < 3; ++c) {
            int idx = c * 4096 + t * 8;
            int row = idx >> 6;
            int kg0 = t & 7;
            f32x4 v0 = *(const f32x4*)(Rg + idx);
            f32x4 v1 = *(const f32x4*)(Rg + idx + 4);
            u32x4 d0;
            d0[0] = pack2(v0[0], v0[1]); d0[1] = pack2(v0[2], v0[3]);
            d0[2] = pack2(v1[0], v1[1]); d0[3] = pack2(v1[2], v1[3]);
            *(u32x4*)&Rl[row * 64 + ((kg0 ^ (row & 7)) << 3)] = d0;
        }
        // stage P^T slice (o = nt*128 .. +128), 16 cols x 1 h per thread
        {
            int h  = t >> 3;               // 0..63
            int og = (t & 7) * 16;
            const float* Pg = project + (size_t)h * OUTF + nt * 128 + og;
#pragma unroll
            for (int q = 0; q < 4; ++q) {
                f32x4 v = *(const f32x4*)(Pg + q * 4);
#pragma unroll
                for (int e = 0; e < 4; ++e) {
                    int o = og + q * 4 + e;
                    Pl[o * 64 + (((h >> 3) ^ (o & 7)) << 3) + (h & 7)] = f2bf(v[e]);
                }
            }
        }
        __syncthreads();   // Rl/Pl ready (also drains A stage(0/1) vm ops)

        // 8-wave W split: wn = w&3 over i (4 x 48), wm = w>>2 over o (2 x 64)
        const int wn = w & 3, wm = w >> 2;
        f32x4 wacc[3][4];
#pragma unroll
        for (int n = 0; n < 3; ++n)
#pragma unroll
            for (int m = 0; m < 4; ++m) wacc[n][m] = f32x4{0.f, 0.f, 0.f, 0.f};

#pragma unroll
        for (int kk = 0; kk < 2; ++kk) {
            int kg = kk * 4 + lk;
            bf16x8 a[4], bb[3];
#pragma unroll
            for (int m = 0; m < 4; ++m) {
                int row = wm * 64 + m * 16 + lr;
                a[m] = *(const bf16x8*)&Pl[row * 64 + ((kg ^ (row & 7)) << 3)];
            }
#pragma unroll
            for (int n = 0; n < 3; ++n) {
                int col = wn * 48 + n * 16 + lr;
                bb[n] = *(const bf16x8*)&Rl[col * 64 + ((kg ^ (col & 7)) << 3)];
            }
#pragma unroll
            for (int n = 0; n < 3; ++n)
#pragma unroll
                for (int m = 0; m < 4; ++m)
                    wacc[n][m] = __builtin_amdgcn_mfma_f32_16x16x32_bf16(
                        bb[n], a[m], wacc[n][m], 0, 0, 0);
        }
        __syncthreads();   // all Rl/Pl reads complete before overwrite

        // store W: D[i = wn*48+n*16+lk*4+j][o = wm*64+m*16+lr] -> b64 each
        uint16_t* Bs16 = (uint16_t*)arena;
#pragma unroll
        for (int n = 0; n < 3; ++n) {
            int ubase = (wn * 6 + n * 2 + (lk >> 1)) * 128;
#pragma unroll
            for (int m = 0; m < 4; ++m) {
                int o = wm * 64 + m * 16 + lr;
                u32x2 d;
                d[0] = pack2(wacc[n][m][0], wacc[n][m][1]);
                d[1] = pack2(wacc[n][m][2], wacc[n][m][3]);
                *(u32x2*)&Bs16[(size_t)(ubase + o) * 8 + (lk & 1) * 4] = d;
            }
        }
        __syncthreads();   // Bs ready
    }

    // ================= main: 12 flat steps, zero barriers ===================
    f32x4 acc[8];
#pragma unroll
    for (int n = 0; n < 8; ++n) acc[n] = f32x4{0.f, 0.f, 0.f, 0.f};

    const int a0s = ((2 * lk)     ^ (lr & 7)) << 4;
    const int a1s = ((2 * lk + 1) ^ (lr & 7)) << 4;

#pragma unroll
    for (int s = 0; s < 12; ++s) {
        const int h  = s / 6;      // half 0..1
        const int kk = s % 6;      // K-step within half

        if (s == 11)                  { WAIT_VM0(); }
        else if (s == 6 || s == 7)    { WAIT_VM10(); }
        else                          { WAIT_VM2(); }
        __builtin_amdgcn_sched_barrier(0);

        const uint8_t* Abuf = Ab + (s & 1) * 2048;
        bf16x8 af, bfr[8];
        {
            const uint8_t* p = Abuf + lr * 128;
            f32x4 lo = *(const f32x4*)(p + a0s);
            f32x4 hi = *(const f32x4*)(p + a1s);
            af = cvt8(lo, hi);
        }
#pragma unroll
        for (int n = 0; n < 8; ++n)
            bfr[n] = *(const bf16x8*)(arena
                        + (((kk * 4 + lk) * 128 + n * 16 + lr) << 4));

        WAIT_LGKM0();                       // buf reads retired before reuse
        __builtin_amdgcn_sched_barrier(0);
        if (s < 10) stage(s + 2, s & 1);    // fire-and-forget, depth-2

        // swapped MFMA: D[o][m]; lane owns 4 consecutive o-cols
#pragma unroll
        for (int n = 0; n < 8; ++n)
            acc[n] = __builtin_amdgcn_mfma_f32_16x16x32_bf16(
                bfr[n], af, acc[n], 0, 0, 0);

        // half boundary: store this half (8 dwordx4/thread), reset acc.
        if (kk == 5) {
            float* yr = Yb + (size_t)(h * 128 + w * 16 + lr) * OUTF + lk * 4;
#pragma unroll
            for (int n = 0; n < 8; ++n)
                *(f32x4*)(yr + n * 16) = acc[n];
            if (s != 11) {
#pragma unroll
                for (int n = 0; n < 8; ++n) acc[n] = f32x4{0.f, 0.f, 0.f, 0.f};
            }
        }
    }
}

extern "C" void kernel_launch(void* const* d_in, const int* in_sizes, int n_in,
                              void* d_out, int out_size, void* d_ws, size_t ws_size,
                              hipStream_t stream) {
    (void)in_sizes; (void)n_in; (void)out_size; (void)d_ws; (void)ws_size;
    const float* state   = (const float*)d_in[0];
    const int*   session = (const int*)  d_in[1];
    const float* readin  = (const float*)d_in[2];
    const float* project = (const float*)d_in[3];
    float*       out     = (float*)d_out;

    hipLaunchKernelGGL(fused_gemm, dim3(1024), dim3(512), 0, stream,
                       state, session, readin, project, out);
}